// Round 11
// baseline (198.931 us; speedup 1.0000x reference)
//
#include <hip/hip_runtime.h>
#include <stdint.h>

// ---------------- fixed problem geometry (validated by out_size) -------------
#define NBATCH   8
#define TT       8
#define NPTS     6890
#define KCLS     7
#define CCH      128
#define BSAMP    64            // NBATCH*TT
#define NOUT     1722          // n = NPTS/4
#define DSUM     512
#define PCADIM   64
#define V3       23106         // 7702*3
#define EPSBN    1e-5f

#define NW       108           // mask words per sample (64 pts each)
#define PCH      512           // points per gather chunk (= 8 mask words)
#define NCHK     14            // ceil(NPTS/512); last chunk = 234 pts
#define CHN      16            // channels per gather block -> 64B line writes
#define CHB      8             // channel blocks
#define NGRP     2             // point groups; block covers 7 chunks = ~14KB/row
#define CPG      7             // chunks per gather block
#define LDSR     516           // padded row length (floats), 16B-aligned rows
#define NGATHER  (BSAMP * CHB * NGRP)   // 1024 = exactly 4/CU, one clean round

#define K1MASK   (BSAMP * 27)  // 1728 mask blocks
#define K1TP     91            // tpose blocks (redundant-MLP) appended to K1
#define VPB      254           // v-range per tpose block; 91*254 >= 23106

// output layout (flat f32)
#define OFF_GV     0
#define OFF_GF     (BSAMP * NOUT * 3)                 // 330624
#define OFF_COEFF  (OFF_GF + BSAMP * NOUT * CCH)      // 14437248
#define OFF_TPOSE  (OFF_COEFF + NBATCH * PCADIM)      // 14437760

// ------- kernel 1: {argmax mask (1728)} || {MLP+tpose (91 blocks)} -----------
__global__ __launch_bounds__(256) void k1_mask_mlp_tpose(
    const float* __restrict__ logits,            // [BSAMP, NPTS, KCLS]
    const int*   __restrict__ d_label,
    unsigned long long* __restrict__ ws_mask,    // [BSAMP, NW]
    const float* __restrict__ gsum,
    const float* __restrict__ W1, const float* __restrict__ b1,
    const float* __restrict__ g1, const float* __restrict__ be1,
    const float* __restrict__ rm1, const float* __restrict__ rv1,
    const float* __restrict__ W2, const float* __restrict__ b2,
    const float* __restrict__ g2, const float* __restrict__ be2,
    const float* __restrict__ rm2, const float* __restrict__ rv2,
    const float* __restrict__ W3, const float* __restrict__ b3,
    const float* __restrict__ comp,
    const float* __restrict__ mean_,
    const float* __restrict__ scale_,
    float* __restrict__ coeff_out,               // d_out + OFF_COEFF
    float* __restrict__ tpose)                   // d_out + OFF_TPOSE
{
    const int tid = threadIdx.x;

    if (blockIdx.x < K1MASK) {
        // ---------------- mask part ----------------
        const int b     = blockIdx.x / 27;
        const int chunk = blockIdx.x % 27;
        const int i     = chunk * 256 + tid;
        const int label = d_label[0];

        bool sel = false;
        if (i < NPTS) {
            const float* p = logits + ((size_t)b * NPTS + i) * KCLS;
            float best = p[0]; int bi = 0;
            #pragma unroll
            for (int k = 1; k < KCLS; ++k) {
                float v = p[k];
                if (v > best) { best = v; bi = k; }
            }
            sel = (bi == label);
        }
        const unsigned long long m = __ballot(sel);
        if ((tid & 63) == 0) {
            const int w = chunk * 4 + (tid >> 6);
            if (w < NW) ws_mask[b * NW + w] = m;
        }
        return;
    }

    // ------------- MLP (redundant per block) + tpose slice -------------
    __shared__ float gs[NBATCH * DSUM];          // 16 KB
    __shared__ float h1[NBATCH * 128];
    __shared__ float h2[NBATCH * 64];
    __shared__ float h3[NBATCH * PCADIM];        // coeff

    for (int o = tid; o < NBATCH * DSUM; o += 256) {
        const int s = o / DSUM, d = o % DSUM;
        const float* p = gsum + ((size_t)s * TT) * DSUM + d;
        float m = p[0];
        #pragma unroll
        for (int t = 1; t < TT; ++t) m = fmaxf(m, p[(size_t)t * DSUM]);
        gs[o] = m;
    }
    __syncthreads();

    for (int o = tid; o < NBATCH * 128; o += 256) {
        const int s = o >> 7, jj = o & 127;
        const float* w  = W1 + (size_t)jj * DSUM;
        const float* gp = gs + s * DSUM;
        float acc = 0.f;
        for (int d = 0; d < DSUM; ++d) acc = fmaf(w[d], gp[d], acc);
        acc += b1[jj];
        acc = (acc - rm1[jj]) * rsqrtf(rv1[jj] + EPSBN) * g1[jj] + be1[jj];
        h1[o] = fmaxf(acc, 0.f);
    }
    __syncthreads();

    for (int o = tid; o < NBATCH * 64; o += 256) {
        const int s = o >> 6, jj = o & 63;
        const float* w  = W2 + (size_t)jj * 128;
        const float* hp = h1 + s * 128;
        float acc = 0.f;
        #pragma unroll
        for (int d = 0; d < 128; ++d) acc = fmaf(w[d], hp[d], acc);
        acc += b2[jj];
        acc = (acc - rm2[jj]) * rsqrtf(rv2[jj] + EPSBN) * g2[jj] + be2[jj];
        h2[o] = fmaxf(acc, 0.f);
    }
    __syncthreads();

    for (int o = tid; o < NBATCH * 64; o += 256) {
        const int s = o >> 6, jj = o & 63;
        const float* w  = W3 + (size_t)jj * 64;
        const float* hp = h2 + s * 64;
        float acc = 0.f;
        #pragma unroll
        for (int d = 0; d < 64; ++d) acc = fmaf(w[d], hp[d], acc);
        acc += b3[jj];
        h3[o] = acc;
        if (blockIdx.x == K1MASK) coeff_out[o] = acc;   // write coeff once
    }
    __syncthreads();

    // tpose slice: v in [vb*VPB, +VPB)
    const int vb = blockIdx.x - K1MASK;
    #pragma unroll 1
    for (int v0 = vb * VPB + tid; v0 < min(vb * VPB + VPB, V3); v0 += 256) {
        float acc[NBATCH];
        #pragma unroll
        for (int s = 0; s < NBATCH; ++s) acc[s] = 0.f;
        for (int k = 0; k < PCADIM; ++k) {
            const float pv = comp[(size_t)k * V3 + v0];
            #pragma unroll
            for (int s = 0; s < NBATCH; ++s)
                acc[s] = fmaf(h3[s * PCADIM + k], pv, acc[s]);
        }
        const float mn = mean_[v0], scl = scale_[v0];
        #pragma unroll
        for (int s = 0; s < NBATCH; ++s)
            tpose[(size_t)s * V3 + v0] = (acc[s] + mn) * scl;
    }
}

// ------- kernel 2: pure gather, 1024 blocks (= exactly 4/CU) -----------------
// Block = (b, cb of 16 ch, g of 7 chunks of 512 pts). Reads float4/lane (1KB
// wave-bursts), consecutive chunks adjacent -> ~14KB sequential run per row.
// Register double-buffered (rc/rn). Writes 64B full-line per selected point.
__global__ __launch_bounds__(256, 4) void k2_gather(
    const float* __restrict__ feature,           // [BSAMP, CCH, NPTS]
    const unsigned long long* __restrict__ ws_mask,
    const float* __restrict__ x,                 // [BSAMP, NPTS, 3]
    float* __restrict__ gv,                      // [BSAMP, NOUT, 3]
    float* __restrict__ gf)                      // [BSAMP, NOUT, CCH]
{
    __shared__ float lds[CHN * LDSR];            // 33024 B
    __shared__ unsigned long long smask[NW];
    __shared__ int  swc[NW];                     // popcount -> exclusive prefix
    __shared__ int  sel_list[8 * 64];            // packed (p | pos<<9) per word
    __shared__ int  s_ns[8];
    __shared__ int  s_cnt;

    const int tid  = threadIdx.x;
    const int gb   = blockIdx.x;
    const int b    = gb >> 4;                    // /16
    const int idx  = gb & 15;                    // share id 0..15
    const int cb   = idx >> 1;                   // 0..7
    const int g    = idx & 1;                    // 0..1

    const int lane = tid & 63;
    const int wv   = tid >> 6;                   // wave -> rows wv*4..wv*4+3
    const int p4   = lane * 4;
    const float* fbase = feature + ((size_t)b * CCH + cb * CHN) * NPTS;

    float4 rc[8], rn[8];

    // 1) prologue: issue chunk g*CPG loads (all full chunks at c0)
    {
        const int i0 = (g * CPG) * PCH;
        #pragma unroll
        for (int it = 0; it < 4; ++it) {
            const float* src = fbase + (size_t)(wv * 4 + it) * NPTS + i0 + p4;
            rc[2 * it]     = *(const float4*)(src);
            rc[2 * it + 1] = *(const float4*)(src + 256);
        }
    }

    // 2) mask + exclusive prefix (hidden under load flight)
    if (tid < NW) smask[tid] = ws_mask[b * NW + tid];
    __syncthreads();
    if (tid < NW) swc[tid] = __popcll(smask[tid]);
    __syncthreads();
    if (tid == 0) {
        int run = 0;
        for (int w = 0; w < NW; ++w) { int t = swc[w]; swc[w] = run; run += t; }
        s_cnt = run < NOUT ? run : NOUT;
    }
    __syncthreads();

    // 3) gv share + gv/gf tail-zero shares (independent stores, hidden)
    {
        const int i0s = idx * 431;
        const int i1s = min(i0s + 431, NPTS);
        const float* xb = x + (size_t)b * NPTS * 3;
        for (int i = i0s + tid; i < i1s; i += 256) {
            const int w = i >> 6, lb6 = i & 63;
            const unsigned long long m = smask[w];
            if ((m >> lb6) & 1ull) {
                const int pos = swc[w] + __popcll(m & ((1ull << lb6) - 1ull));
                if (pos < NOUT) {
                    const size_t go = ((size_t)b * NOUT + pos) * 3;
                    gv[go + 0] = xb[(size_t)i * 3 + 0];
                    gv[go + 1] = xb[(size_t)i * 3 + 1];
                    gv[go + 2] = xb[(size_t)i * 3 + 2];
                }
            }
        }
        const int cnt  = s_cnt;
        const int tail = NOUT - cnt;
        if (tail > 0) {
            const int share = (tail + 15) / 16;
            const int r0    = cnt + idx * share;
            const int r1    = min(r0 + share, NOUT);
            if (r1 > r0) {
                for (int j = r0 + tid; j < r1; j += 256) {
                    float* gp = gv + ((size_t)b * NOUT + j) * 3;
                    gp[0] = 0.f; gp[1] = 0.f; gp[2] = 0.f;
                }
                float4* base4 = (float4*)(gf + ((size_t)b * NOUT + r0) * CCH);
                const int total = (r1 - r0) * 32;
                for (int f = tid; f < total; f += 256)
                    base4[f] = make_float4(0.f, 0.f, 0.f, 0.f);
            }
        }
    }

    // 4) pipelined chunk loop (reg double-buffer, 2 barriers/chunk)
    #pragma unroll 1
    for (int c = 0; c < CPG; ++c) {
        const int chunk = g * CPG + c;

        if (c + 1 < CPG) {
            const int nchunk = chunk + 1;
            const int i1 = nchunk * PCH;
            if (nchunk != NCHK - 1) {
                #pragma unroll
                for (int it = 0; it < 4; ++it) {
                    const float* src = fbase + (size_t)(wv * 4 + it) * NPTS + i1 + p4;
                    rn[2 * it]     = *(const float4*)(src);
                    rn[2 * it + 1] = *(const float4*)(src + 256);
                }
            } else {
                // tail chunk (234 pts): guarded float2 pairs packed into rn
                const int il = NPTS - i1;        // 234
                const int o1 = lane * 2;         // 0..126
                const int o2 = 128 + lane * 2;   // 128..254
                #pragma unroll
                for (int it = 0; it < 4; ++it) {
                    const float* src = fbase + (size_t)(wv * 4 + it) * NPTS + i1;
                    float2 a = *(const float2*)(src + o1);
                    float2 bv = (o2 < il) ? *(const float2*)(src + o2)
                                          : make_float2(0.f, 0.f);
                    rn[2 * it] = make_float4(a.x, a.y, bv.x, bv.y);
                }
            }
        }

        __syncthreads();                         // LDS + sel arrays free

        // LDS write
        if (chunk != NCHK - 1) {
            #pragma unroll
            for (int it = 0; it < 4; ++it) {
                const int r = wv * 4 + it;
                *(float4*)(&lds[r * LDSR + p4])       = rc[2 * it];
                *(float4*)(&lds[r * LDSR + 256 + p4]) = rc[2 * it + 1];
            }
        } else {
            const int il = NPTS - chunk * PCH;   // 234
            const int o1 = lane * 2;
            const int o2 = 128 + lane * 2;
            #pragma unroll
            for (int it = 0; it < 4; ++it) {
                const int r = wv * 4 + it;
                *(float2*)(&lds[r * LDSR + o1]) = make_float2(rc[2*it].x, rc[2*it].y);
                if (o2 < il)
                    *(float2*)(&lds[r * LDSR + o2]) = make_float2(rc[2*it].z, rc[2*it].w);
            }
        }

        // selection for this chunk's 8 words (waves own 2 words each)
        #pragma unroll
        for (int j = 0; j < 2; ++j) {
            const int wk   = 2 * wv + j;         // 0..7
            const int word = chunk * 8 + wk;
            unsigned long long m = 0; int base = 0;
            if (word < NW) { m = smask[word]; base = swc[word]; }
            const int sel = (int)((m >> lane) & 1ull);
            const int pos = base + __popcll(m & ((1ull << lane) - 1ull));
            const bool ok = sel && pos < NOUT;
            const unsigned long long mm = __ballot(ok);
            const int before = __popcll(mm & ((1ull << lane) - 1ull));
            if (ok) sel_list[wk * 64 + before] = (wk * 64 + lane) | (pos << 9);
            if (lane == 0) s_ns[wk] = __popcll(mm);
        }

        __syncthreads();                         // LDS writes + sel visible

        // phase B: 64B full-line writes, 4 points per wave-op, 2-deep pipeline
        {
            const int q  = lane >> 4;            // 0..3
            const int ch = lane & 15;
            float* gfb = gf + (size_t)b * NOUT * CCH + cb * CHN + ch;
            #pragma unroll
            for (int j = 0; j < 2; ++j) {
                const int wk = 2 * wv + j;
                const int ns = s_ns[wk];
                int s = q;
                if (s < ns) {
                    int e = sel_list[wk * 64 + s];
                    int p = e & 511, pos = e >> 9;
                    float v = lds[ch * LDSR + p];
                    for (s += 4; s < ns; s += 4) {
                        const int e2 = sel_list[wk * 64 + s];
                        const int p2 = e2 & 511, pos2 = e2 >> 9;
                        const float v2 = lds[ch * LDSR + p2];
                        gfb[(size_t)pos * CCH] = v;
                        v = v2; pos = pos2;
                    }
                    gfb[(size_t)pos * CCH] = v;
                }
            }
        }

        if (c + 1 < CPG) {
            #pragma unroll
            for (int it = 0; it < 8; ++it) rc[it] = rn[it];
        }
    }
}

// ---------------- launcher ---------------------------------------------------
extern "C" void kernel_launch(void* const* d_in, const int* in_sizes, int n_in,
                              void* d_out, int out_size, void* d_ws, size_t ws_size,
                              hipStream_t stream) {
    const float* x      = (const float*)d_in[0];
    const float* logits = (const float*)d_in[1];
    const float* feat   = (const float*)d_in[2];
    const float* gsum   = (const float*)d_in[3];
    const float* W1  = (const float*)d_in[4];
    const float* b1  = (const float*)d_in[5];
    const float* g1  = (const float*)d_in[6];
    const float* be1 = (const float*)d_in[7];
    const float* rm1 = (const float*)d_in[8];
    const float* rv1 = (const float*)d_in[9];
    const float* W2  = (const float*)d_in[10];
    const float* b2  = (const float*)d_in[11];
    const float* g2  = (const float*)d_in[12];
    const float* be2 = (const float*)d_in[13];
    const float* rm2 = (const float*)d_in[14];
    const float* rv2 = (const float*)d_in[15];
    const float* W3  = (const float*)d_in[16];
    const float* b3  = (const float*)d_in[17];
    const float* comp  = (const float*)d_in[18];
    const float* mean_ = (const float*)d_in[19];
    const float* scale_= (const float*)d_in[20];
    const int* d_label = (const int*)d_in[21];

    float* out   = (float*)d_out;
    float* gv    = out + OFF_GV;
    float* gf    = out + OFF_GF;
    float* coeff = out + OFF_COEFF;
    float* tpose = out + OFF_TPOSE;

    unsigned long long* ws_mask = (unsigned long long*)d_ws;      // 64*108 u64

    k1_mask_mlp_tpose<<<K1MASK + K1TP, 256, 0, stream>>>(
        logits, d_label, ws_mask, gsum, W1, b1, g1, be1, rm1, rv1,
        W2, b2, g2, be2, rm2, rv2, W3, b3, comp, mean_, scale_,
        coeff, tpose);

    k2_gather<<<NGATHER, 256, 0, stream>>>(
        feat, ws_mask, x, gv, gf);
}

// Round 12
// 97.952 us; speedup vs baseline: 2.0309x; 2.0309x over previous
//
#include <hip/hip_runtime.h>
#include <stdint.h>

// ---------------- fixed problem geometry (validated by out_size) -------------
#define NBATCH   8
#define TT       8
#define NPTS     6890
#define KCLS     7
#define CCH      128
#define BSAMP    64            // NBATCH*TT
#define NOUT     1722          // n = NPTS/4
#define DSUM     512
#define PCADIM   64
#define V3       23106         // 7702*3
#define EPSBN    1e-5f

#define NW       108           // mask words per sample (64 pts each)
#define PCH      512           // points per gather chunk (= 8 mask words)
#define NCHK     14            // ceil(NPTS/512); last chunk = 234 pts
#define CHN      16            // channels per gather block -> 64B line writes
#define CHB      8             // channel blocks
#define NGRP     2             // point groups; block covers 7 chunks = ~14KB/row
#define CPG      7             // chunks per gather block
#define LDSR     516           // padded row length (floats), 16B-aligned rows
#define K4B      91            // tpose blocks (first in k2 grid)
#define NGATHER  (BSAMP * CHB * NGRP)   // 1024 gather blocks (4/CU, balanced)

// output layout (flat f32)
#define OFF_GV     0
#define OFF_GF     (BSAMP * NOUT * 3)                 // 330624
#define OFF_COEFF  (OFF_GF + BSAMP * NOUT * CCH)      // 14437248
#define OFF_TPOSE  (OFF_COEFF + NBATCH * PCADIM)      // 14437760

// ------- kernel 1: {argmax mask (1728 blocks)} || {MLP (8 blocks)} -----------
__global__ __launch_bounds__(256) void k1_mask_mlp(
    const float* __restrict__ logits,            // [BSAMP, NPTS, KCLS]
    const int*   __restrict__ d_label,
    unsigned long long* __restrict__ ws_mask,    // [BSAMP, NW]
    const float* __restrict__ gsum,
    const float* __restrict__ W1, const float* __restrict__ b1,
    const float* __restrict__ g1, const float* __restrict__ be1,
    const float* __restrict__ rm1, const float* __restrict__ rv1,
    const float* __restrict__ W2, const float* __restrict__ b2,
    const float* __restrict__ g2, const float* __restrict__ be2,
    const float* __restrict__ rm2, const float* __restrict__ rv2,
    const float* __restrict__ W3, const float* __restrict__ b3,
    float* __restrict__ coeff_out, float* __restrict__ coeff_ws)
{
    const int tid = threadIdx.x;

    if (blockIdx.x < BSAMP * 27) {
        // ---------------- mask part ----------------
        const int b     = blockIdx.x / 27;
        const int chunk = blockIdx.x % 27;
        const int i     = chunk * 256 + tid;
        const int label = d_label[0];

        bool sel = false;
        if (i < NPTS) {
            const float* p = logits + ((size_t)b * NPTS + i) * KCLS;
            float best = p[0]; int bi = 0;
            #pragma unroll
            for (int k = 1; k < KCLS; ++k) {
                float v = p[k];
                if (v > best) { best = v; bi = k; }
            }
            sel = (bi == label);
        }
        const unsigned long long m = __ballot(sel);
        if ((tid & 63) == 0) {
            const int w = chunk * 4 + (tid >> 6);
            if (w < NW) ws_mask[b * NW + w] = m;
        }
    } else {
        // ---------------- MLP part (8 blocks, wave-coop coalesced dots) ------
        const int s    = blockIdx.x - BSAMP * 27;
        const int lane = tid & 63;
        const int wv   = tid >> 6;

        __shared__ float gs[DSUM];
        __shared__ float h1[128];
        __shared__ float h2[64];

        for (int d = tid; d < DSUM; d += 256) {
            const float* p = gsum + ((size_t)s * TT) * DSUM + d;
            float m = p[0];
            #pragma unroll
            for (int t = 1; t < TT; ++t) m = fmaxf(m, p[(size_t)t * DSUM]);
            gs[d] = m;
        }
        __syncthreads();

        for (int r = 0; r < 32; r += 2) {
            const int j0 = wv * 32 + r, j1 = j0 + 1;
            const float* w0 = W1 + (size_t)j0 * DSUM;
            const float* w1 = W1 + (size_t)j1 * DSUM;
            float pa = 0.f, pb = 0.f;
            #pragma unroll
            for (int d = lane; d < DSUM; d += 64) {
                const float gd = gs[d];
                pa = fmaf(w0[d], gd, pa);
                pb = fmaf(w1[d], gd, pb);
            }
            #pragma unroll
            for (int off = 32; off; off >>= 1) {
                pa += __shfl_xor(pa, off);
                pb += __shfl_xor(pb, off);
            }
            if (lane == 0) {
                pa += b1[j0];
                pa = (pa - rm1[j0]) * rsqrtf(rv1[j0] + EPSBN) * g1[j0] + be1[j0];
                h1[j0] = fmaxf(pa, 0.f);
                pb += b1[j1];
                pb = (pb - rm1[j1]) * rsqrtf(rv1[j1] + EPSBN) * g1[j1] + be1[j1];
                h1[j1] = fmaxf(pb, 0.f);
            }
        }
        __syncthreads();

        for (int r = 0; r < 16; ++r) {
            const int jj = wv * 16 + r;
            const float* w = W2 + (size_t)jj * 128;
            float p = w[lane] * h1[lane] + w[lane + 64] * h1[lane + 64];
            #pragma unroll
            for (int off = 32; off; off >>= 1) p += __shfl_xor(p, off);
            if (lane == 0) {
                p += b2[jj];
                p = (p - rm2[jj]) * rsqrtf(rv2[jj] + EPSBN) * g2[jj] + be2[jj];
                h2[jj] = fmaxf(p, 0.f);
            }
        }
        __syncthreads();

        for (int r = 0; r < 16; ++r) {
            const int jj = wv * 16 + r;
            float p = W3[(size_t)jj * 64 + lane] * h2[lane];
            #pragma unroll
            for (int off = 32; off; off >>= 1) p += __shfl_xor(p, off);
            if (lane == 0) {
                p += b3[jj];
                coeff_out[s * PCADIM + jj] = p;
                coeff_ws[s * PCADIM + jj]  = p;
            }
        }
    }
}

// ------- kernel 2: {tpose (91)} || {gather (1024 = 4/CU, balanced)} ----------
// Gather block = (b, cb of 16 ch, g of 7 chunks of 512 pts). Reads float4/lane
// (1KB wave-bursts), 7 adjacent chunks -> ~14KB sequential run per channel row.
// Register double-buffered. Writes 64B full-line per selected point.
__global__ __launch_bounds__(256, 4) void k2_all(
    const float* __restrict__ feature,           // [BSAMP, CCH, NPTS]
    const unsigned long long* __restrict__ ws_mask,
    const float* __restrict__ x,                 // [BSAMP, NPTS, 3]
    float* __restrict__ gv,                      // [BSAMP, NOUT, 3]
    float* __restrict__ gf,                      // [BSAMP, NOUT, CCH]
    const float* __restrict__ coeff_ws,
    const float* __restrict__ comp,
    const float* __restrict__ mean_,
    const float* __restrict__ scale_,
    float* __restrict__ tpose)
{
    __shared__ float lds[CHN * LDSR];            // 33024 B
    __shared__ unsigned long long smask[NW];
    __shared__ int  swc[NW];                     // popcount -> exclusive prefix
    __shared__ int  sel_list[8 * 64];            // packed (p | pos<<9) per word
    __shared__ int  s_ns[8];
    __shared__ int  s_cnt;

    const int tid = threadIdx.x;

    if (blockIdx.x < K4B) {
        // ---------------- tpose part ----------------
        float* sc = lds;
        for (int o = tid; o < NBATCH * PCADIM; o += 256) sc[o] = coeff_ws[o];
        __syncthreads();

        const int v = blockIdx.x * 256 + tid;
        if (v >= V3) return;

        float acc[NBATCH];
        #pragma unroll
        for (int s = 0; s < NBATCH; ++s) acc[s] = 0.f;
        for (int k = 0; k < PCADIM; ++k) {
            const float pv = comp[(size_t)k * V3 + v];
            #pragma unroll
            for (int s = 0; s < NBATCH; ++s)
                acc[s] = fmaf(sc[s * PCADIM + k], pv, acc[s]);
        }
        const float mn = mean_[v], scl = scale_[v];
        #pragma unroll
        for (int s = 0; s < NBATCH; ++s)
            tpose[(size_t)s * V3 + v] = (acc[s] + mn) * scl;
        return;
    }

    // ---------------- gather part ----------------
    const int gb   = blockIdx.x - K4B;
    const int b    = gb >> 4;                    // /16
    const int idx  = gb & 15;                    // share id 0..15
    const int cb   = idx >> 1;                   // 0..7
    const int g    = idx & 1;                    // 0..1

    const int lane = tid & 63;
    const int wv   = tid >> 6;                   // wave -> rows wv*4..wv*4+3
    const int p4   = lane * 4;
    const float* fbase = feature + ((size_t)b * CCH + cb * CHN) * NPTS;

    float4 rc[8], rn[8];

    // 1) prologue: issue chunk g*CPG loads (c0 is always a full chunk)
    {
        const int i0 = (g * CPG) * PCH;
        #pragma unroll
        for (int it = 0; it < 4; ++it) {
            const float* src = fbase + (size_t)(wv * 4 + it) * NPTS + i0 + p4;
            rc[2 * it]     = *(const float4*)(src);
            rc[2 * it + 1] = *(const float4*)(src + 256);
        }
    }

    // 2) mask + exclusive prefix (hidden under load flight)
    if (tid < NW) smask[tid] = ws_mask[b * NW + tid];
    __syncthreads();
    if (tid < NW) swc[tid] = __popcll(smask[tid]);
    __syncthreads();
    if (tid == 0) {
        int run = 0;
        for (int w = 0; w < NW; ++w) { int t = swc[w]; swc[w] = run; run += t; }
        s_cnt = run < NOUT ? run : NOUT;
    }
    __syncthreads();

    // 3) gv share + gv/gf tail-zero shares (independent stores, hidden)
    {
        const int i0s = idx * 431;
        const int i1s = min(i0s + 431, NPTS);
        const float* xb = x + (size_t)b * NPTS * 3;
        for (int i = i0s + tid; i < i1s; i += 256) {
            const int w = i >> 6, lb6 = i & 63;
            const unsigned long long m = smask[w];
            if ((m >> lb6) & 1ull) {
                const int pos = swc[w] + __popcll(m & ((1ull << lb6) - 1ull));
                if (pos < NOUT) {
                    const size_t go = ((size_t)b * NOUT + pos) * 3;
                    gv[go + 0] = xb[(size_t)i * 3 + 0];
                    gv[go + 1] = xb[(size_t)i * 3 + 1];
                    gv[go + 2] = xb[(size_t)i * 3 + 2];
                }
            }
        }
        const int cnt  = s_cnt;
        const int tail = NOUT - cnt;
        if (tail > 0) {
            const int share = (tail + 15) / 16;
            const int r0    = cnt + idx * share;
            const int r1    = min(r0 + share, NOUT);
            if (r1 > r0) {
                for (int j = r0 + tid; j < r1; j += 256) {
                    float* gp = gv + ((size_t)b * NOUT + j) * 3;
                    gp[0] = 0.f; gp[1] = 0.f; gp[2] = 0.f;
                }
                float4* base4 = (float4*)(gf + ((size_t)b * NOUT + r0) * CCH);
                const int total = (r1 - r0) * 32;
                for (int f = tid; f < total; f += 256)
                    base4[f] = make_float4(0.f, 0.f, 0.f, 0.f);
            }
        }
    }

    // 4) pipelined chunk loop (reg double-buffer, 2 barriers/chunk)
    #pragma unroll 1
    for (int c = 0; c < CPG; ++c) {
        const int chunk = g * CPG + c;

        if (c + 1 < CPG) {
            const int nchunk = chunk + 1;
            const int i1 = nchunk * PCH;
            if (nchunk != NCHK - 1) {
                #pragma unroll
                for (int it = 0; it < 4; ++it) {
                    const float* src = fbase + (size_t)(wv * 4 + it) * NPTS + i1 + p4;
                    rn[2 * it]     = *(const float4*)(src);
                    rn[2 * it + 1] = *(const float4*)(src + 256);
                }
            } else {
                // tail chunk (234 pts): guarded float2 pairs packed into rn
                const int il = NPTS - i1;        // 234
                const int o1 = lane * 2;         // 0..126
                const int o2 = 128 + lane * 2;   // 128..254
                #pragma unroll
                for (int it = 0; it < 4; ++it) {
                    const float* src = fbase + (size_t)(wv * 4 + it) * NPTS + i1;
                    float2 a = *(const float2*)(src + o1);
                    float2 bv = (o2 < il) ? *(const float2*)(src + o2)
                                          : make_float2(0.f, 0.f);
                    rn[2 * it] = make_float4(a.x, a.y, bv.x, bv.y);
                }
            }
        }

        __syncthreads();                         // LDS + sel arrays free

        // LDS write (point-indexed layout in both paths)
        if (chunk != NCHK - 1) {
            #pragma unroll
            for (int it = 0; it < 4; ++it) {
                const int r = wv * 4 + it;
                *(float4*)(&lds[r * LDSR + p4])       = rc[2 * it];
                *(float4*)(&lds[r * LDSR + 256 + p4]) = rc[2 * it + 1];
            }
        } else {
            const int il = NPTS - chunk * PCH;   // 234
            const int o1 = lane * 2;
            const int o2 = 128 + lane * 2;
            #pragma unroll
            for (int it = 0; it < 4; ++it) {
                const int r = wv * 4 + it;
                *(float2*)(&lds[r * LDSR + o1]) = make_float2(rc[2*it].x, rc[2*it].y);
                if (o2 < il)
                    *(float2*)(&lds[r * LDSR + o2]) = make_float2(rc[2*it].z, rc[2*it].w);
            }
        }

        // selection for this chunk's 8 words (waves own 2 words each)
        #pragma unroll
        for (int j = 0; j < 2; ++j) {
            const int wk   = 2 * wv + j;         // 0..7
            const int word = chunk * 8 + wk;
            unsigned long long m = 0; int base = 0;
            if (word < NW) { m = smask[word]; base = swc[word]; }
            const int sel = (int)((m >> lane) & 1ull);
            const int pos = base + __popcll(m & ((1ull << lane) - 1ull));
            const bool ok = sel && pos < NOUT;
            const unsigned long long mm = __ballot(ok);
            const int before = __popcll(mm & ((1ull << lane) - 1ull));
            if (ok) sel_list[wk * 64 + before] = (wk * 64 + lane) | (pos << 9);
            if (lane == 0) s_ns[wk] = __popcll(mm);
        }

        __syncthreads();                         // LDS writes + sel visible

        // phase B: 64B full-line writes, 4 points per wave-op, 2-deep pipeline
        {
            const int q  = lane >> 4;            // 0..3
            const int ch = lane & 15;
            float* gfb = gf + (size_t)b * NOUT * CCH + cb * CHN + ch;
            #pragma unroll
            for (int j = 0; j < 2; ++j) {
                const int wk = 2 * wv + j;
                const int ns = s_ns[wk];
                int s = q;
                if (s < ns) {
                    int e = sel_list[wk * 64 + s];
                    int p = e & 511, pos = e >> 9;
                    float v = lds[ch * LDSR + p];
                    for (s += 4; s < ns; s += 4) {
                        const int e2 = sel_list[wk * 64 + s];
                        const int p2 = e2 & 511, pos2 = e2 >> 9;
                        const float v2 = lds[ch * LDSR + p2];
                        gfb[(size_t)pos * CCH] = v;
                        v = v2; pos = pos2;
                    }
                    gfb[(size_t)pos * CCH] = v;
                }
            }
        }

        if (c + 1 < CPG) {
            #pragma unroll
            for (int it = 0; it < 8; ++it) rc[it] = rn[it];
        }
    }
}

// ---------------- launcher ---------------------------------------------------
extern "C" void kernel_launch(void* const* d_in, const int* in_sizes, int n_in,
                              void* d_out, int out_size, void* d_ws, size_t ws_size,
                              hipStream_t stream) {
    const float* x      = (const float*)d_in[0];
    const float* logits = (const float*)d_in[1];
    const float* feat   = (const float*)d_in[2];
    const float* gsum   = (const float*)d_in[3];
    const float* W1  = (const float*)d_in[4];
    const float* b1  = (const float*)d_in[5];
    const float* g1  = (const float*)d_in[6];
    const float* be1 = (const float*)d_in[7];
    const float* rm1 = (const float*)d_in[8];
    const float* rv1 = (const float*)d_in[9];
    const float* W2  = (const float*)d_in[10];
    const float* b2  = (const float*)d_in[11];
    const float* g2  = (const float*)d_in[12];
    const float* be2 = (const float*)d_in[13];
    const float* rm2 = (const float*)d_in[14];
    const float* rv2 = (const float*)d_in[15];
    const float* W3  = (const float*)d_in[16];
    const float* b3  = (const float*)d_in[17];
    const float* comp  = (const float*)d_in[18];
    const float* mean_ = (const float*)d_in[19];
    const float* scale_= (const float*)d_in[20];
    const int* d_label = (const int*)d_in[21];

    float* out   = (float*)d_out;
    float* gv    = out + OFF_GV;
    float* gf    = out + OFF_GF;
    float* coeff = out + OFF_COEFF;
    float* tpose = out + OFF_TPOSE;

    unsigned long long* ws_mask = (unsigned long long*)d_ws;      // 64*108 u64
    float* coeff_ws = (float*)(ws_mask + BSAMP * NW);             // 512 f32

    k1_mask_mlp<<<BSAMP * 27 + NBATCH, 256, 0, stream>>>(
        logits, d_label, ws_mask, gsum, W1, b1, g1, be1, rm1, rv1,
        W2, b2, g2, be2, rm2, rv2, W3, b3, coeff, coeff_ws);

    k2_all<<<K4B + NGATHER, 256, 0, stream>>>(
        feat, ws_mask, x, gv, gf, coeff_ws, comp, mean_, scale_, tpose);
}